// Round 6
// baseline (81.081 us; speedup 1.0000x reference)
//
#include <hip/hip_runtime.h>

// Problem constants (match reference)
#define BB 2
#define NN 131072
#define MM 512
#define GG 20
#define VV (GG * GG * GG)      // 8000
#define NBLKX 128              // blocks per batch for min/accum

// Workspace layout:
//   0       partialMin : B*NBLKX*3 floats (3072 B)  -- written K1
//   3072    minVals    : B*3 floats (24 B)          -- written K2 (redundant, same values)
//   3200    sflat      : B*M ints (4096 B)          -- written K2
//   8192    flags      : B*V bytes (16000 B, pad 16384) -- zeroed K1, set K2
//   24576   sums       : B*V*10 floats (640000 B)   -- flagged entries zeroed K2, atomics K3
#define OFF_PARTIAL 0
#define OFF_MINV    3072
#define OFF_SFLAT   3200
#define OFF_FLAGS   8192
#define OFF_SUMS    24576
#define FLAGWORDS   (16384 / 4)   // 4096

__device__ __forceinline__ int vox_coord(float p, float mn) {
    int i = (int)floorf((p - mn) * 2.0f);   // *2 == /0.5 (exact pow2 scale)
    return min(max(i, 0), GG - 1);
}

// ---- K1: zero flags (16 KB) + per-block coordinate-min partials --------
__global__ __launch_bounds__(256) void vox_min(const float* __restrict__ x,
                                               char* __restrict__ ws) {
    const int b = blockIdx.y;
    const int tid = blockIdx.x * 256 + threadIdx.x;                 // per batch
    const int gtid = (b * NBLKX + blockIdx.x) * 256 + threadIdx.x;  // global

    if (gtid < FLAGWORDS) ((int*)(ws + OFF_FLAGS))[gtid] = 0;

    // one group of 3 float4 (= 4 points) per thread
    const float4* xb = (const float4*)(x + (size_t)b * NN * 3);
    float4 f0 = xb[3 * tid + 0];
    float4 f1 = xb[3 * tid + 1];
    float4 f2 = xb[3 * tid + 2];
    float mx = fminf(fminf(f0.x, f0.w), fminf(f1.z, f2.y));
    float my = fminf(fminf(f0.y, f1.x), fminf(f1.w, f2.z));
    float mz = fminf(fminf(f0.z, f1.y), fminf(f2.x, f2.w));

    for (int off = 32; off > 0; off >>= 1) {
        mx = fminf(mx, __shfl_down(mx, off, 64));
        my = fminf(my, __shfl_down(my, off, 64));
        mz = fminf(mz, __shfl_down(mz, off, 64));
    }
    __shared__ float lmin[4][3];
    int wave = threadIdx.x >> 6;
    if ((threadIdx.x & 63) == 0) {
        lmin[wave][0] = mx; lmin[wave][1] = my; lmin[wave][2] = mz;
    }
    __syncthreads();
    if (threadIdx.x == 0) {
        float* pm = (float*)(ws + OFF_PARTIAL) + (b * NBLKX + blockIdx.x) * 3;
        pm[0] = fminf(fminf(lmin[0][0], lmin[1][0]), fminf(lmin[2][0], lmin[3][0]));
        pm[1] = fminf(fminf(lmin[0][1], lmin[1][1]), fminf(lmin[2][1], lmin[3][1]));
        pm[2] = fminf(fminf(lmin[0][2], lmin[1][2]), fminf(lmin[2][2], lmin[3][2]));
    }
}

// ---- K2: reduce partials + mark sampled voxels + zero flagged sums -----
// 2 blocks x 512 threads; each block redundantly reduces the partials
// (L2-hot, 384 B of data) then marks a disjoint half of the samples.
__global__ __launch_bounds__(512) void vox_mark(const float* __restrict__ x,
                                                const int* __restrict__ sidx,
                                                char* __restrict__ ws) {
    __shared__ float smin[BB][3];
    const int t = threadIdx.x;

    // 6 (b,axis) pairs x 64 lanes: each lane folds 2 of the 128 partials
    if (t < 384) {
        int pair = t >> 6;            // 0..5
        int lane = t & 63;
        int pb = pair / 3, axis = pair % 3;
        const float* pm = (const float*)(ws + OFF_PARTIAL);
        float m = fminf(pm[(pb * NBLKX + lane) * 3 + axis],
                        pm[(pb * NBLKX + lane + 64) * 3 + axis]);
        for (int off = 32; off > 0; off >>= 1)
            m = fminf(m, __shfl_down(m, off, 64));
        if (lane == 0) {
            smin[pb][axis] = m;
            ((float*)(ws + OFF_MINV))[pb * 3 + axis] = m;  // same value both blocks
        }
    }
    __syncthreads();

    // mark: global sample s in [0, B*M)
    int s = blockIdx.x * 512 + t;
    int b = s >> 9;                   // s / M (M=512)
    int pi = sidx[s];
    const float* p = x + ((size_t)b * NN + pi) * 3;
    int ix = vox_coord(p[0], smin[b][0]);
    int iy = vox_coord(p[1], smin[b][1]);
    int iz = vox_coord(p[2], smin[b][2]);
    int flat = (ix * GG + iy) * GG + iz;
    ((int*)(ws + OFF_SFLAT))[s] = flat;
    ((unsigned char*)(ws + OFF_FLAGS))[b * VV + flat] = 1;

    // zero this flagged voxel's sums (duplicates write the same zeros)
    float* sz = (float*)(ws + OFF_SUMS) + ((size_t)b * VV + flat) * 10;
#pragma unroll
    for (int k = 0; k < 10; ++k) sz[k] = 0.0f;
}

// ---- K3: accumulate sums for flagged voxels ----------------------------
// sums per (b,voxel): [cnt, sx, sy, sz, sxx, sxy, sxz, syy, syz, szz]
__global__ __launch_bounds__(256) void vox_accum(const float* __restrict__ x,
                                                 char* __restrict__ ws) {
    const int b = blockIdx.y;
    const int tid = blockIdx.x * 256 + threadIdx.x;
    const float* mv = (const float*)(ws + OFF_MINV) + b * 3;
    const float mnx = mv[0], mny = mv[1], mnz = mv[2];
    const unsigned char* flags = (const unsigned char*)(ws + OFF_FLAGS) + b * VV;
    float* sums = (float*)(ws + OFF_SUMS) + (size_t)b * VV * 10;

    const float4* xb = (const float4*)(x + (size_t)b * NN * 3);
    float4 f0 = xb[3 * tid + 0];
    float4 f1 = xb[3 * tid + 1];
    float4 f2 = xb[3 * tid + 2];
    float px[4] = {f0.x, f0.w, f1.z, f2.y};
    float py[4] = {f0.y, f1.x, f1.w, f2.z};
    float pz[4] = {f0.z, f1.y, f2.x, f2.w};
#pragma unroll
    for (int k = 0; k < 4; ++k) {
        int ix = vox_coord(px[k], mnx);
        int iy = vox_coord(py[k], mny);
        int iz = vox_coord(pz[k], mnz);
        int flat = (ix * GG + iy) * GG + iz;
        if (flags[flat]) {
            float* s = sums + (size_t)flat * 10;
            atomicAdd(s + 0, 1.0f);
            atomicAdd(s + 1, px[k]);
            atomicAdd(s + 2, py[k]);
            atomicAdd(s + 3, pz[k]);
            atomicAdd(s + 4, px[k] * px[k]);
            atomicAdd(s + 5, px[k] * py[k]);
            atomicAdd(s + 6, px[k] * pz[k]);
            atomicAdd(s + 7, py[k] * py[k]);
            atomicAdd(s + 8, py[k] * pz[k]);
            atomicAdd(s + 9, pz[k] * pz[k]);
        }
    }
}

// ---- K4: finalize mean/cov at sampled voxels ---------------------------
__global__ __launch_bounds__(256) void vox_final(const char* __restrict__ ws,
                                                 float* __restrict__ out) {
    int t = blockIdx.x * 256 + threadIdx.x;
    if (t >= BB * MM) return;
    int b = t >> 9;
    int flat = ((const int*)(ws + OFF_SFLAT))[t];
    const float* s = (const float*)(ws + OFF_SUMS) + ((size_t)b * VV + flat) * 10;
    float cnt = s[0];
    float inv = 1.0f / fmaxf(cnt, 1.0f);
    float mx = s[1] * inv, my = s[2] * inv, mz = s[3] * inv;
    float cxx = s[4] * inv - mx * mx;
    float cxy = s[5] * inv - mx * my;
    float cxz = s[6] * inv - mx * mz;
    float cyy = s[7] * inv - my * my;
    float cyz = s[8] * inv - my * mz;
    float czz = s[9] * inv - mz * mz;
    float* o = out + (size_t)t * 12;
    o[0] = mx;  o[1] = my;  o[2] = mz;
    o[3] = cxx; o[4] = cxy; o[5] = cxz;
    o[6] = cxy; o[7] = cyy; o[8] = cyz;
    o[9] = cxz; o[10] = cyz; o[11] = czz;
}

extern "C" void kernel_launch(void* const* d_in, const int* in_sizes, int n_in,
                              void* d_out, int out_size, void* d_ws, size_t ws_size,
                              hipStream_t stream) {
    const float* x = (const float*)d_in[0];   // (B, N, 3) fp32
    const int* sidx = (const int*)d_in[1];    // (B, M) int32
    float* out = (float*)d_out;               // (B, M, 12) fp32
    char* ws = (char*)d_ws;

    vox_min<<<dim3(NBLKX, BB), 256, 0, stream>>>(x, ws);
    vox_mark<<<2, 512, 0, stream>>>(x, sidx, ws);
    vox_accum<<<dim3(NBLKX, BB), 256, 0, stream>>>(x, ws);
    vox_final<<<(BB * MM + 255) / 256, 256, 0, stream>>>(ws, out);
}